// Round 6
// baseline (164.876 us; speedup 1.0000x reference)
//
#include <hip/hip_runtime.h>

#define KP   15
#define HN   40
#define CIN  128
#define COUT 128
#define KDIM (KP*CIN)          // 1920
#define KP_EXT_INV (1.0f/1.2f)

typedef __bf16 bf16x8 __attribute__((ext_vector_type(8)));
typedef __bf16 bf16x4 __attribute__((ext_vector_type(4)));
typedef float  f32x4  __attribute__((ext_vector_type(4)));

__device__ inline void async_copy16(const void* g, void* lds) {
    __builtin_amdgcn_global_load_lds(
        (const __attribute__((address_space(1))) unsigned int*)g,
        (__attribute__((address_space(3))) unsigned int*)lds, 16, 0, 0);
}
#define LGKM0() __asm__ __volatile__("s_waitcnt lgkmcnt(0)" ::: "memory")

// ---------------------------------------------------------------------------
// Kernel 1 (prep): x f32 -> xb bf16 (coalesced); W [1920][128] -> Wt [128][1920]
// ---------------------------------------------------------------------------
__global__ __launch_bounds__(256)
void kpconv_prep(const float* __restrict__ x, const float* __restrict__ W,
                 __bf16* __restrict__ xb, __bf16* __restrict__ Wt,
                 int nx_elems, int nxB)
{
    __shared__ float sW[32][133];
    const int b = blockIdx.x;
    const int t = threadIdx.x;

    if (b < nxB) {
        const int e0 = (b*256 + t) * 8;
        if (e0 + 8 <= nx_elems) {
            const float4 f0 = *(const float4*)(x + e0);
            const float4 f1 = *(const float4*)(x + e0 + 4);
            bf16x8 v;
            v[0]=(__bf16)f0.x; v[1]=(__bf16)f0.y; v[2]=(__bf16)f0.z; v[3]=(__bf16)f0.w;
            v[4]=(__bf16)f1.x; v[5]=(__bf16)f1.y; v[6]=(__bf16)f1.z; v[7]=(__bf16)f1.w;
            *(bf16x8*)(xb + e0) = v;
        } else {
            for (int e = e0; e < nx_elems; ++e) xb[e] = (__bf16)x[e];
        }
    } else {
        const int kc0 = (b - nxB) * 32;
        #pragma unroll
        for (int i = 0; i < 4; ++i) {
            const int off = t*4 + i*1024;
            const int r = off >> 7, c = off & 127;
            const float4 f = *(const float4*)(W + (size_t)(kc0 + r)*COUT + c);
            sW[r][c+0]=f.x; sW[r][c+1]=f.y; sW[r][c+2]=f.z; sW[r][c+3]=f.w;
        }
        __syncthreads();
        #pragma unroll
        for (int i = 0; i < 2; ++i) {
            const int id = t + i*256;
            const int d  = id >> 2, ch = id & 3;
            bf16x8 v;
            #pragma unroll
            for (int j = 0; j < 8; ++j) v[j] = (__bf16)sW[ch*8 + j][d];
            *(bf16x8*)(Wt + (size_t)d*KDIM + kc0 + ch*8) = v;
        }
    }
}

// ---------------------------------------------------------------------------
// Kernel 2: aggregation. 1 wave = 2 points (register-pipelined), 4 waves/block.
// All 20 gathers issued up-front; point 1's latency hides under point 0's
// LDS-transpose + MFMA + epilogue. Weights via d^2 = |nd|^2+|kp|^2-2 nd.kp.
// ---------------------------------------------------------------------------
__global__ __launch_bounds__(256, 3)
void kpconv_aggregate(const float* __restrict__ q_pts,
                      const float* __restrict__ s_pts,
                      const int*   __restrict__ nb,
                      const __bf16* __restrict__ xb,
                      const float* __restrict__ kpts,
                      __bf16* __restrict__ wsA,
                      int N, int Ns)
{
    __shared__ __align__(16) __bf16 sXt[4][4][128][8];  // 32 KB (reused per pt)
    __shared__ __align__(16) float4 s_nd[4][2][HN];
    __shared__ int                  s_idx[4][2][HN];

    const int t  = threadIdx.x;
    const int wv = t >> 6;
    const int l  = t & 63;
    const int m  = l & 15;
    const int q  = l >> 4;
    const int nbase = (blockIdx.x*4 + wv)*2;

    // ---- geometry, both points; |nd|^2 stashed in .w ----
    #pragma unroll
    for (int pp = 0; pp < 2; ++pp) {
        if (l < HN) {
            const int n = nbase + pp;
            int idx = nb[n*HN + l];
            float dx, dy, dz;
            if (idx >= 0 && idx < Ns) {
                dx = s_pts[idx*3+0] - q_pts[n*3+0];
                dy = s_pts[idx*3+1] - q_pts[n*3+1];
                dz = s_pts[idx*3+2] - q_pts[n*3+2];
            } else { idx = 0; dx = dy = dz = 2.0e6f; }
            s_idx[wv][pp][l] = idx;
            s_nd[wv][pp][l]  = make_float4(dx, dy, dz, dx*dx + dy*dy + dz*dz);
        }
    }
    LGKM0();

    // ---- issue ALL 20 gathers (2 pts x 5 iters x 2 rows) into registers ----
    // iter 0..3: h0 = 8*it + 2*q (ks0); iter 4: h0 = 32 + 2*q (ks1)
    uint4 g[2][5][2];
    #pragma unroll
    for (int pp = 0; pp < 2; ++pp) {
        #pragma unroll
        for (int it = 0; it < 5; ++it) {
            const int h0 = (it < 4) ? (it*8 + 2*q) : (32 + 2*q);
            g[pp][it][0] = *(const uint4*)(xb + (size_t)s_idx[wv][pp][h0  ]*CIN + m*8);
            g[pp][it][1] = *(const uint4*)(xb + (size_t)s_idx[wv][pp][h0+1]*CIN + m*8);
        }
    }

    // ---- influence weights for both points (overlaps gather latency) ----
    float kx=0.f, ky=0.f, kz=0.f;
    if (m < KP) { kx = kpts[m*3+0]; ky = kpts[m*3+1]; kz = kpts[m*3+2]; }
    const float kk  = kx*kx + ky*ky + kz*kz;
    const float kx2 = -2.f*kx, ky2 = -2.f*ky, kz2 = -2.f*kz;

    bf16x8 wfrag[2][2];
    #pragma unroll
    for (int pp = 0; pp < 2; ++pp) {
        #pragma unroll
        for (int ks = 0; ks < 2; ++ks) {
            #pragma unroll
            for (int j = 0; j < 8; ++j) {
                const int h = ks*32 + q*8 + j;
                float w = 0.f;
                if (m < KP && h < HN) {
                    const float4 nd = s_nd[wv][pp][h];
                    const float d2 = fmaf(nd.x, kx2,
                                     fmaf(nd.y, ky2,
                                     fmaf(nd.z, kz2, nd.w + kk)));
                    const float d = __builtin_amdgcn_sqrtf(d2);
                    w = fmaxf(fmaf(d, -KP_EXT_INV, 1.0f), 0.f);
                }
                wfrag[pp][ks][j] = (__bf16)w;
            }
        }
    }

    // ---- process the two points sequentially ----
    #pragma unroll
    for (int pp = 0; pp < 2; ++pp) {
        const int n = nbase + pp;
        f32x4 acc[8];
        #pragma unroll
        for (int nt = 0; nt < 8; ++nt) acc[nt] = (f32x4){0.f,0.f,0.f,0.f};

        #pragma unroll
        for (int ks = 0; ks < 2; ++ks) {
            const int itBeg = ks ? 4 : 0;
            const int itEnd = ks ? 5 : 4;
            #pragma unroll
            for (int it = itBeg; it < itEnd; ++it) {
                const unsigned av[4] = {g[pp][it][0].x, g[pp][it][0].y,
                                        g[pp][it][0].z, g[pp][it][0].w};
                const unsigned bv[4] = {g[pp][it][1].x, g[pp][it][1].y,
                                        g[pp][it][1].z, g[pp][it][1].w};
                const int hc = ks ? 0 : it;          // plane
                const int dw = q;                    // dword within 16B chunk
                unsigned* plane = (unsigned*)&sXt[wv][hc][0][0];
                #pragma unroll
                for (int j = 0; j < 8; ++j) {
                    const unsigned v = __builtin_amdgcn_perm(
                        bv[j>>1], av[j>>1], (j&1) ? 0x07060302u : 0x05040100u);
                    const int p = m*8 + (j ^ (m & 7));
                    plane[p*4 + dw] = v;
                }
            }
            LGKM0();

            // x as A-frag A[m=c][k=h]; ks=1 stale planes killed by w=0 (h>=40)
            #pragma unroll
            for (int nt = 0; nt < 8; ++nt) {
                const int cc = nt*16 + m;
                const int p  = (cc & ~7) | ((cc & 7) ^ ((cc >> 3) & 7));
                bf16x8 xf = *(const bf16x8*)&sXt[wv][q][p][0];
                acc[nt] = __builtin_amdgcn_mfma_f32_16x16x32_bf16(
                              xf, wfrag[pp][ks], acc[nt], 0, 0, 0);
            }
        }

        // epilogue: D[row=c=q*4+r+16nt][col=kpt=m] -> wsA, bf16x4 stores
        if (m < KP) {
            #pragma unroll
            for (int nt = 0; nt < 8; ++nt) {
                bf16x4 v;
                #pragma unroll
                for (int r = 0; r < 4; ++r) v[r] = (__bf16)acc[nt][r];
                *(bf16x4*)(wsA + (size_t)n*KDIM + m*CIN + nt*16 + q*4) = v;
            }
        }
    }
}

// ---------------------------------------------------------------------------
// Kernel 3: out[M][128] = A[M][1920] x Wt[128][1920]^T, f32 out.
// BM=32 (625 blocks). A staged via 8 KB LDS DMA; B-frags DIRECT from
// L2-resident Wt (no sB, no B-barrier). 16 MFMA/wave/iter.
// ---------------------------------------------------------------------------
#define GBM 32

__global__ __launch_bounds__(256, 4)
void kpconv_gemm(const __bf16* __restrict__ A,
                 const __bf16* __restrict__ Bt,
                 float* __restrict__ out, int M)
{
    __shared__ __align__(16) __bf16 sA[GBM*128];   // 8 KB

    const int t     = threadIdx.x;
    const int wv    = t >> 6;
    const int l     = t & 63;
    const int mlane = l & 15;
    const int q     = l >> 4;
    const int m0    = blockIdx.x * GBM;

    const int r0  = t >> 4;    // 0..15 (pass adds 16)
    const int pos = t & 15;    // stored chunk position

    const __bf16* Brow0 = Bt + (size_t)(wv*32 + mlane) * KDIM;
    const __bf16* Brow1 = Brow0 + (size_t)16 * KDIM;

    f32x4 acc[2][2];
    #pragma unroll
    for (int i = 0; i < 2; ++i)
        #pragma unroll
        for (int j = 0; j < 2; ++j) acc[i][j] = (f32x4){0.f,0.f,0.f,0.f};

    for (int k0 = 0; k0 < KDIM; k0 += 128) {
        #pragma unroll
        for (int p = 0; p < 2; ++p) {
            const int row = r0 + p*16;
            const int ch  = pos ^ (row & 15);
            async_copy16(A + (size_t)(m0 + row)*KDIM + k0 + ch*8,
                         (char*)sA + (p*256 + t)*16);
        }
        __syncthreads();

        bf16x8 bfr[2][4];
        #pragma unroll
        for (int ks = 0; ks < 4; ++ks) {
            bfr[0][ks] = *(const bf16x8*)(Brow0 + k0 + ks*32 + q*8);
            bfr[1][ks] = *(const bf16x8*)(Brow1 + k0 + ks*32 + q*8);
        }

        #pragma unroll
        for (int ks = 0; ks < 4; ++ks) {
            bf16x8 af[2];
            #pragma unroll
            for (int mt = 0; mt < 2; ++mt) {
                const int row = mt*16 + mlane;
                const int p   = (ks*4 + q) ^ (row & 15);
                af[mt] = *(const bf16x8*)&sA[row*128 + p*8];
            }
            #pragma unroll
            for (int mt = 0; mt < 2; ++mt)
                #pragma unroll
                for (int j = 0; j < 2; ++j)
                    acc[mt][j] = __builtin_amdgcn_mfma_f32_16x16x32_bf16(
                                     af[mt], bfr[j][ks], acc[mt][j], 0, 0, 0);
        }
        __syncthreads();
    }

    #pragma unroll
    for (int mt = 0; mt < 2; ++mt)
        #pragma unroll
        for (int j = 0; j < 2; ++j)
            #pragma unroll
            for (int r = 0; r < 4; ++r)
                out[(size_t)(m0 + mt*16 + q*4 + r)*COUT + wv*32 + j*16 + mlane]
                    = acc[mt][j][r];
}

// ---------------------------------------------------------------------------
// Fallback (round-1 fused kernel) if ws too small
// ---------------------------------------------------------------------------
#define TM 8
#define WSTR (KP*CIN + 4)

__global__ __launch_bounds__(256, 2)
void kpconv_fused(const float* __restrict__ q_pts,
                  const float* __restrict__ s_pts,
                  const int*   __restrict__ nb,
                  const float* __restrict__ x,
                  const float* __restrict__ kpts,
                  const float* __restrict__ W,
                  float* __restrict__ out,
                  int N, int Ns)
{
    __shared__ float s_kp[KP*3];
    __shared__ float s_nd2[HN*3];
    __shared__ int   s_idx2[HN];
    __shared__ float s_w[KP][HN];
    __shared__ float s_wt[TM*WSTR];

    const int t  = threadIdx.x;
    const int n0 = (int)blockIdx.x * TM;
    if (t < KP*3) s_kp[t] = kpts[t];
    const int c = t & (CIN-1);
    const int g = t >> 7;

    for (int mm = 0; mm < TM; ++mm) {
        const int n = n0 + mm;
        if (t < HN) {
            float dx = 1e6f, dy = 1e6f, dz = 1e6f;
            int idx = 0;
            if (n < N) {
                idx = nb[n*HN + t];
                if (idx >= 0 && idx < Ns) {
                    dx = s_pts[idx*3+0] - q_pts[n*3+0];
                    dy = s_pts[idx*3+1] - q_pts[n*3+1];
                    dz = s_pts[idx*3+2] - q_pts[n*3+2];
                } else idx = 0;
            }
            s_idx2[t] = idx;
            s_nd2[t*3+0] = dx; s_nd2[t*3+1] = dy; s_nd2[t*3+2] = dz;
        }
        __syncthreads();
        for (int task = t; task < KP*HN; task += 256) {
            const int k = task / HN;
            const int h = task - k*HN;
            const float dx = s_nd2[h*3+0] - s_kp[k*3+0];
            const float dy = s_nd2[h*3+1] - s_kp[k*3+1];
            const float dz = s_nd2[h*3+2] - s_kp[k*3+2];
            s_w[k][h] = fmaxf(1.0f - sqrtf(dx*dx+dy*dy+dz*dz)*KP_EXT_INV, 0.0f);
        }
        __syncthreads();
        float facc[8];
        #pragma unroll
        for (int j = 0; j < 8; ++j) facc[j] = 0.0f;
        #pragma unroll 8
        for (int h = 0; h < HN; ++h) {
            const float xv = x[s_idx2[h]*CIN + c];
            #pragma unroll
            for (int j = 0; j < 8; ++j) {
                const int k = g + 2*j;
                if (k < KP) facc[j] += s_w[k][h] * xv;
            }
        }
        #pragma unroll
        for (int j = 0; j < 8; ++j) {
            const int k = g + 2*j;
            if (k < KP) s_wt[mm*WSTR + k*CIN + c] = facc[j];
        }
        __syncthreads();
    }

    const int m3 = t >> 5;
    const int d0 = (t & 31) * 4;
    const float* wm = &s_wt[m3*WSTR];
    float ax = 0.f, ay = 0.f, az = 0.f, aw = 0.f;
    #pragma unroll 4
    for (int kc = 0; kc < KP*CIN; ++kc) {
        const float  wvv = wm[kc];
        const float4 wr = *(const float4*)&W[kc*COUT + d0];
        ax += wvv * wr.x; ay += wvv * wr.y; az += wvv * wr.z; aw += wvv * wr.w;
    }
    const int n = n0 + m3;
    if (n < N) {
        float4 o; o.x = ax; o.y = ay; o.z = az; o.w = aw;
        *(float4*)&out[n*COUT + d0] = o;
    }
}

// ---------------------------------------------------------------------------
extern "C" void kernel_launch(void* const* d_in, const int* in_sizes, int n_in,
                              void* d_out, int out_size, void* d_ws, size_t ws_size,
                              hipStream_t stream) {
    const float* q_pts = (const float*)d_in[0];
    const float* s_pts = (const float*)d_in[1];
    const int*   nb    = (const int*)  d_in[2];
    const float* x     = (const float*)d_in[3];
    const float* kpts  = (const float*)d_in[4];
    const float* W     = (const float*)d_in[5];
    float* out = (float*)d_out;

    const int N  = in_sizes[0] / 3;
    const int Ns = in_sizes[1] / 3;
    const int nx = in_sizes[3];            // Ns*CIN

    const size_t needA = (size_t)N * KDIM * sizeof(__bf16);
    const size_t needB = (size_t)COUT * KDIM * sizeof(__bf16);
    const size_t needX = (size_t)nx * sizeof(__bf16);

    if (ws_size >= needA + needB + needX && (N % 8) == 0 && (N % GBM) == 0
        && (KDIM % 128) == 0) {
        __bf16* wsA = (__bf16*)d_ws;
        __bf16* wsB = (__bf16*)((char*)d_ws + needA);
        __bf16* wsX = (__bf16*)((char*)d_ws + needA + needB);

        const int nxB = (nx/8 + 255) / 256;
        const int nwB = KDIM / 32;
        hipLaunchKernelGGL(kpconv_prep, dim3(nxB + nwB), dim3(256), 0, stream,
                           x, W, wsX, wsB, nx, nxB);
        hipLaunchKernelGGL(kpconv_aggregate, dim3(N/8), dim3(256), 0, stream,
                           q_pts, s_pts, nb, wsX, kpts, wsA, N, Ns);
        hipLaunchKernelGGL(kpconv_gemm, dim3(N/GBM), dim3(256), 0, stream,
                           wsA, wsB, out, N);
    } else {
        const int grid = (N + TM - 1) / TM;
        hipLaunchKernelGGL(kpconv_fused, dim3(grid), dim3(256), 0, stream,
                           q_pts, s_pts, nb, x, kpts, W, out, N, Ns);
    }
}

// Round 7
// 144.116 us; speedup vs baseline: 1.1440x; 1.1440x over previous
//
#include <hip/hip_runtime.h>

#define KP   15
#define HN   40
#define CIN  128
#define COUT 128
#define KDIM (KP*CIN)          // 1920
#define KP_EXT_INV (1.0f/1.2f)

typedef __bf16 bf16x8 __attribute__((ext_vector_type(8)));
typedef __bf16 bf16x4 __attribute__((ext_vector_type(4)));
typedef float  f32x4  __attribute__((ext_vector_type(4)));

__device__ inline void async_copy16(const void* g, void* lds) {
    __builtin_amdgcn_global_load_lds(
        (const __attribute__((address_space(1))) unsigned int*)g,
        (__attribute__((address_space(3))) unsigned int*)lds, 16, 0, 0);
}
#define LGKM0() __asm__ __volatile__("s_waitcnt lgkmcnt(0)" ::: "memory")

// ---------------------------------------------------------------------------
// Kernel 1 (prep): x f32 -> xb bf16 (coalesced); W [1920][128] -> Wt [128][1920]
// ---------------------------------------------------------------------------
__global__ __launch_bounds__(256)
void kpconv_prep(const float* __restrict__ x, const float* __restrict__ W,
                 __bf16* __restrict__ xb, __bf16* __restrict__ Wt,
                 int nx_elems, int nxB)
{
    __shared__ float sW[32][133];
    const int b = blockIdx.x;
    const int t = threadIdx.x;

    if (b < nxB) {
        const int e0 = (b*256 + t) * 8;
        if (e0 + 8 <= nx_elems) {
            const float4 f0 = *(const float4*)(x + e0);
            const float4 f1 = *(const float4*)(x + e0 + 4);
            bf16x8 v;
            v[0]=(__bf16)f0.x; v[1]=(__bf16)f0.y; v[2]=(__bf16)f0.z; v[3]=(__bf16)f0.w;
            v[4]=(__bf16)f1.x; v[5]=(__bf16)f1.y; v[6]=(__bf16)f1.z; v[7]=(__bf16)f1.w;
            *(bf16x8*)(xb + e0) = v;
        } else {
            for (int e = e0; e < nx_elems; ++e) xb[e] = (__bf16)x[e];
        }
    } else {
        const int kc0 = (b - nxB) * 32;
        #pragma unroll
        for (int i = 0; i < 4; ++i) {
            const int off = t*4 + i*1024;
            const int r = off >> 7, c = off & 127;
            const float4 f = *(const float4*)(W + (size_t)(kc0 + r)*COUT + c);
            sW[r][c+0]=f.x; sW[r][c+1]=f.y; sW[r][c+2]=f.z; sW[r][c+3]=f.w;
        }
        __syncthreads();
        #pragma unroll
        for (int i = 0; i < 2; ++i) {
            const int id = t + i*256;
            const int d  = id >> 2, ch = id & 3;
            bf16x8 v;
            #pragma unroll
            for (int j = 0; j < 8; ++j) v[j] = (__bf16)sW[ch*8 + j][d];
            *(bf16x8*)(Wt + (size_t)d*KDIM + kc0 + ch*8) = v;
        }
    }
}

// ---------------------------------------------------------------------------
// Kernel 2: aggregation. 1 BLOCK = 1 WAVE = 1 point. ~9 KB LDS ->
// 16 independent waves/CU, zero inter-wave barriers, all syncs lgkmcnt-only.
// ---------------------------------------------------------------------------
__global__ __launch_bounds__(64, 4)
void kpconv_aggregate(const float* __restrict__ q_pts,
                      const float* __restrict__ s_pts,
                      const int*   __restrict__ nb,
                      const __bf16* __restrict__ xb,
                      const float* __restrict__ kpts,
                      __bf16* __restrict__ wsA,
                      int N, int Ns)
{
    __shared__ __align__(16) __bf16 sXt[4][128][8];  // 8 KB
    __shared__ __align__(16) float4 s_nd[HN];
    __shared__ int                  s_idx[HN];

    const int l = threadIdx.x;     // 0..63
    const int m = l & 15;
    const int q = l >> 4;
    const int n = blockIdx.x;

    // ---- geometry; |nd|^2 stashed in .w ----
    if (l < HN) {
        int idx = nb[n*HN + l];
        float dx, dy, dz;
        if (idx >= 0 && idx < Ns) {
            dx = s_pts[idx*3+0] - q_pts[n*3+0];
            dy = s_pts[idx*3+1] - q_pts[n*3+1];
            dz = s_pts[idx*3+2] - q_pts[n*3+2];
        } else { idx = 0; dx = dy = dz = 2.0e6f; }
        s_idx[l] = idx;
        s_nd[l]  = make_float4(dx, dy, dz, dx*dx + dy*dy + dz*dz);
    }
    LGKM0();   // single wave: writes now visible

    // ---- issue all 10 gathers ----
    // iter 0..3: rows (8it+2q, +1); iter 4: rows (32+2q, +1)
    uint4 g[5][2];
    #pragma unroll
    for (int it = 0; it < 5; ++it) {
        const int h0 = (it < 4) ? (it*8 + 2*q) : (32 + 2*q);
        g[it][0] = *(const uint4*)(xb + (size_t)s_idx[h0  ]*CIN + m*8);
        g[it][1] = *(const uint4*)(xb + (size_t)s_idx[h0+1]*CIN + m*8);
    }

    // ---- influence weights (independent of gathers; overlaps latency) ----
    float kx=0.f, ky=0.f, kz=0.f;
    if (m < KP) { kx = kpts[m*3+0]; ky = kpts[m*3+1]; kz = kpts[m*3+2]; }
    const float kk  = kx*kx + ky*ky + kz*kz;
    const float kx2 = -2.f*kx, ky2 = -2.f*ky, kz2 = -2.f*kz;

    bf16x8 wfrag[2];
    #pragma unroll
    for (int ks = 0; ks < 2; ++ks) {
        #pragma unroll
        for (int j = 0; j < 8; ++j) {
            const int h = ks*32 + q*8 + j;
            float w = 0.f;
            if (m < KP && h < HN) {
                const float4 nd = s_nd[h];
                const float d2 = fmaf(nd.x, kx2,
                                 fmaf(nd.y, ky2,
                                 fmaf(nd.z, kz2, nd.w + kk)));
                const float d = __builtin_amdgcn_sqrtf(d2);
                w = fmaxf(fmaf(d, -KP_EXT_INV, 1.0f), 0.f);
            }
            wfrag[ks][j] = (__bf16)w;
        }
    }

    f32x4 acc[8];
    #pragma unroll
    for (int nt = 0; nt < 8; ++nt) acc[nt] = (f32x4){0.f,0.f,0.f,0.f};

    #pragma unroll
    for (int ks = 0; ks < 2; ++ks) {
        const int itBeg = ks ? 4 : 0;
        const int itEnd = ks ? 5 : 4;
        #pragma unroll
        for (int it = itBeg; it < itEnd; ++it) {
            const unsigned av[4] = {g[it][0].x, g[it][0].y, g[it][0].z, g[it][0].w};
            const unsigned bv[4] = {g[it][1].x, g[it][1].y, g[it][1].z, g[it][1].w};
            const int hc = ks ? 0 : it;          // plane
            unsigned* plane = (unsigned*)&sXt[hc][0][0];
            #pragma unroll
            for (int j = 0; j < 8; ++j) {
                const unsigned v = __builtin_amdgcn_perm(
                    bv[j>>1], av[j>>1], (j&1) ? 0x07060302u : 0x05040100u);
                const int p = m*8 + (j ^ (m & 7));
                plane[p*4 + q] = v;
            }
        }
        LGKM0();

        // x as A-frag A[m=c][k=h]; ks=1 stale planes 1..3 killed by w=0 (h>=40)
        #pragma unroll
        for (int nt = 0; nt < 8; ++nt) {
            const int cc = nt*16 + m;
            const int p  = (cc & ~7) | ((cc & 7) ^ ((cc >> 3) & 7));
            bf16x8 xf = *(const bf16x8*)&sXt[q][p][0];
            acc[nt] = __builtin_amdgcn_mfma_f32_16x16x32_bf16(
                          xf, wfrag[ks], acc[nt], 0, 0, 0);
        }
    }

    // ---- epilogue: D[row=c=q*4+r+16nt][col=kpt=m] -> wsA bf16x4 stores ----
    if (m < KP) {
        #pragma unroll
        for (int nt = 0; nt < 8; ++nt) {
            bf16x4 v;
            #pragma unroll
            for (int r = 0; r < 4; ++r) v[r] = (__bf16)acc[nt][r];
            *(bf16x4*)(wsA + (size_t)n*KDIM + m*CIN + nt*16 + q*4) = v;
        }
    }
}

// ---------------------------------------------------------------------------
// Kernel 3: out[M][128] += A[M][1920] x Wt[128][1920]^T, split-K x2.
// BM=32, BK=128, staged sA+sB (40 KB), grid (M/32, 2) = 4.9 blocks/CU.
// Epilogue: f32 atomicAdd (out zero-initialized by hipMemsetAsync).
// ---------------------------------------------------------------------------
#define GBM 32
#define GBK 128

__global__ __launch_bounds__(256, 4)
void kpconv_gemm(const __bf16* __restrict__ A,
                 const __bf16* __restrict__ Bt,
                 float* __restrict__ out, int M)
{
    __shared__ __align__(16) __bf16 sA[GBM*GBK];    // 8 KB
    __shared__ __align__(16) __bf16 sB[COUT*GBK];   // 32 KB

    const int t     = threadIdx.x;
    const int wv    = t >> 6;
    const int l     = t & 63;
    const int mlane = l & 15;
    const int q     = l >> 4;
    const int m0    = blockIdx.x * GBM;

    const int itBeg = blockIdx.y ? 8 : 0;
    const int itEnd = blockIdx.y ? 15 : 8;

    const int rA = t >> 4;   // 0..15
    const int pA = t & 15;   // stored chunk pos; logical ch c at pos c^(row&15)

    f32x4 acc[2][2];
    #pragma unroll
    for (int i = 0; i < 2; ++i)
        #pragma unroll
        for (int j = 0; j < 2; ++j) acc[i][j] = (f32x4){0.f,0.f,0.f,0.f};

    for (int it = itBeg; it < itEnd; ++it) {
        const int k0 = it * GBK;
        #pragma unroll
        for (int pass = 0; pass < 2; ++pass) {
            const int r  = rA + pass*16;
            const int ch = pA ^ (r & 15);
            async_copy16(A + (size_t)(m0 + r)*KDIM + k0 + ch*8,
                         (char*)sA + pass*4096 + wv*1024 + l*16);
        }
        #pragma unroll
        for (int pass = 0; pass < 8; ++pass) {
            const int r  = rA + pass*16;
            const int ch = pA ^ (r & 15);
            async_copy16(Bt + (size_t)r*KDIM + k0 + ch*8,
                         (char*)sB + pass*4096 + wv*1024 + l*16);
        }
        __syncthreads();

        #pragma unroll
        for (int ks = 0; ks < 4; ++ks) {
            bf16x8 af[2], bfr[2];
            #pragma unroll
            for (int mt = 0; mt < 2; ++mt) {
                const int row = mt*16 + mlane;
                const int p   = (ks*4 + q) ^ (row & 15);
                af[mt] = *(const bf16x8*)&sA[row*GBK + p*8];
            }
            #pragma unroll
            for (int j = 0; j < 2; ++j) {
                const int row = (wv*2 + j)*16 + mlane;
                const int p   = (ks*4 + q) ^ (row & 15);
                bfr[j] = *(const bf16x8*)&sB[row*GBK + p*8];
            }
            #pragma unroll
            for (int mt = 0; mt < 2; ++mt)
                #pragma unroll
                for (int j = 0; j < 2; ++j)
                    acc[mt][j] = __builtin_amdgcn_mfma_f32_16x16x32_bf16(
                                     af[mt], bfr[j], acc[mt][j], 0, 0, 0);
        }
        __syncthreads();
    }

    #pragma unroll
    for (int mt = 0; mt < 2; ++mt)
        #pragma unroll
        for (int j = 0; j < 2; ++j)
            #pragma unroll
            for (int r = 0; r < 4; ++r)
                atomicAdd(&out[(size_t)(m0 + mt*16 + q*4 + r)*COUT
                               + (wv*2+j)*16 + mlane], acc[mt][j][r]);
}

// ---------------------------------------------------------------------------
// Fallback (round-1 fused kernel) if ws too small
// ---------------------------------------------------------------------------
#define TM 8
#define WSTR (KP*CIN + 4)

__global__ __launch_bounds__(256, 2)
void kpconv_fused(const float* __restrict__ q_pts,
                  const float* __restrict__ s_pts,
                  const int*   __restrict__ nb,
                  const float* __restrict__ x,
                  const float* __restrict__ kpts,
                  const float* __restrict__ W,
                  float* __restrict__ out,
                  int N, int Ns)
{
    __shared__ float s_kp[KP*3];
    __shared__ float s_nd2[HN*3];
    __shared__ int   s_idx2[HN];
    __shared__ float s_w[KP][HN];
    __shared__ float s_wt[TM*WSTR];

    const int t  = threadIdx.x;
    const int n0 = (int)blockIdx.x * TM;
    if (t < KP*3) s_kp[t] = kpts[t];
    const int c = t & (CIN-1);
    const int g = t >> 7;

    for (int mm = 0; mm < TM; ++mm) {
        const int n = n0 + mm;
        if (t < HN) {
            float dx = 1e6f, dy = 1e6f, dz = 1e6f;
            int idx = 0;
            if (n < N) {
                idx = nb[n*HN + t];
                if (idx >= 0 && idx < Ns) {
                    dx = s_pts[idx*3+0] - q_pts[n*3+0];
                    dy = s_pts[idx*3+1] - q_pts[n*3+1];
                    dz = s_pts[idx*3+2] - q_pts[n*3+2];
                } else idx = 0;
            }
            s_idx2[t] = idx;
            s_nd2[t*3+0] = dx; s_nd2[t*3+1] = dy; s_nd2[t*3+2] = dz;
        }
        __syncthreads();
        for (int task = t; task < KP*HN; task += 256) {
            const int k = task / HN;
            const int h = task - k*HN;
            const float dx = s_nd2[h*3+0] - s_kp[k*3+0];
            const float dy = s_nd2[h*3+1] - s_kp[k*3+1];
            const float dz = s_nd2[h*3+2] - s_kp[k*3+2];
            s_w[k][h] = fmaxf(1.0f - sqrtf(dx*dx+dy*dy+dz*dz)*KP_EXT_INV, 0.0f);
        }
        __syncthreads();
        float facc[8];
        #pragma unroll
        for (int j = 0; j < 8; ++j) facc[j] = 0.0f;
        #pragma unroll 8
        for (int h = 0; h < HN; ++h) {
            const float xv = x[s_idx2[h]*CIN + c];
            #pragma unroll
            for (int j = 0; j < 8; ++j) {
                const int k = g + 2*j;
                if (k < KP) facc[j] += s_w[k][h] * xv;
            }
        }
        #pragma unroll
        for (int j = 0; j < 8; ++j) {
            const int k = g + 2*j;
            if (k < KP) s_wt[mm*WSTR + k*CIN + c] = facc[j];
        }
        __syncthreads();
    }

    const int m3 = t >> 5;
    const int d0 = (t & 31) * 4;
    const float* wm = &s_wt[m3*WSTR];
    float ax = 0.f, ay = 0.f, az = 0.f, aw = 0.f;
    #pragma unroll 4
    for (int kc = 0; kc < KP*CIN; ++kc) {
        const float  wvv = wm[kc];
        const float4 wr = *(const float4*)&W[kc*COUT + d0];
        ax += wvv * wr.x; ay += wvv * wr.y; az += wvv * wr.z; aw += wvv * wr.w;
    }
    const int n = n0 + m3;
    if (n < N) {
        float4 o; o.x = ax; o.y = ay; o.z = az; o.w = aw;
        *(float4*)&out[n*COUT + d0] = o;
    }
}

// ---------------------------------------------------------------------------
extern "C" void kernel_launch(void* const* d_in, const int* in_sizes, int n_in,
                              void* d_out, int out_size, void* d_ws, size_t ws_size,
                              hipStream_t stream) {
    const float* q_pts = (const float*)d_in[0];
    const float* s_pts = (const float*)d_in[1];
    const int*   nb    = (const int*)  d_in[2];
    const float* x     = (const float*)d_in[3];
    const float* kpts  = (const float*)d_in[4];
    const float* W     = (const float*)d_in[5];
    float* out = (float*)d_out;

    const int N  = in_sizes[0] / 3;
    const int Ns = in_sizes[1] / 3;
    const int nx = in_sizes[3];            // Ns*CIN

    const size_t needA = (size_t)N * KDIM * sizeof(__bf16);
    const size_t needB = (size_t)COUT * KDIM * sizeof(__bf16);
    const size_t needX = (size_t)nx * sizeof(__bf16);

    if (ws_size >= needA + needB + needX && (N % GBM) == 0 && (KDIM % 128) == 0) {
        __bf16* wsA = (__bf16*)d_ws;
        __bf16* wsB = (__bf16*)((char*)d_ws + needA);
        __bf16* wsX = (__bf16*)((char*)d_ws + needA + needB);

        const int nxB = (nx/8 + 255) / 256;
        const int nwB = KDIM / 32;
        hipMemsetAsync(out, 0, (size_t)out_size * sizeof(float), stream);
        hipLaunchKernelGGL(kpconv_prep, dim3(nxB + nwB), dim3(256), 0, stream,
                           x, W, wsX, wsB, nx, nxB);
        hipLaunchKernelGGL(kpconv_aggregate, dim3(N), dim3(64), 0, stream,
                           q_pts, s_pts, nb, wsX, kpts, wsA, N, Ns);
        hipLaunchKernelGGL(kpconv_gemm, dim3(N/GBM, 2), dim3(256), 0, stream,
                           wsA, wsB, out, N);
    } else {
        const int grid = (N + TM - 1) / TM;
        hipLaunchKernelGGL(kpconv_fused, dim3(grid), dim3(256), 0, stream,
                           q_pts, s_pts, nb, x, kpts, W, out, N, Ns);
    }
}